// Round 9
// baseline (827.001 us; speedup 1.0000x reference)
//
#include <hip/hip_runtime.h>
#include <math.h>

#define NN 50000
#define NE 800000
#define HID 128

typedef __attribute__((ext_vector_type(8))) short short8;
typedef __attribute__((ext_vector_type(4))) float f32x4;

#define MFMA(a, b, c) __builtin_amdgcn_mfma_f32_16x16x32_bf16(a, b, c, 0, 0, 0)

__device__ __forceinline__ float silu_(float x) {
    return x / (1.0f + __expf(-x));
}

__device__ __forceinline__ float bf2f(short x) {
    union { unsigned u; float f; } v;
    v.u = ((unsigned)(unsigned short)x) << 16;
    return v.f;
}

// f32 -> bf16 bits, round-to-nearest-even
__device__ __forceinline__ short f2bf(float f) {
    union { float f; unsigned u; } v;
    v.f = f;
    unsigned r = v.u + 0x7fffu + ((v.u >> 16) & 1u);
    return (short)(r >> 16);
}

__device__ __forceinline__ short8 pack8(float4 lo, float4 hi) {
    short8 v;
    v[0] = f2bf(lo.x); v[1] = f2bf(lo.y); v[2] = f2bf(lo.z); v[3] = f2bf(lo.w);
    v[4] = f2bf(hi.x); v[5] = f2bf(hi.y); v[6] = f2bf(hi.z); v[7] = f2bf(hi.w);
    return v;
}

// L1 fuse: silu(E + P1 + P2) elementwise on bf16 octets
__device__ __forceinline__ short8 fuse_silu(short8 e, short8 p1, short8 p2) {
    short8 o;
#pragma unroll
    for (int i = 0; i < 8; ++i)
        o[i] = f2bf(silu_(bf2f(e[i]) + bf2f(p1[i]) + bf2f(p2[i])));
    return o;
}

// packed bf16 atomic add: adds 2 bf16 lanes at *p (4B aligned)
__device__ __forceinline__ void atom_pk_bf16(short* p, unsigned pk) {
    asm volatile("global_atomic_pk_add_bf16 %0, %1, off"
                 :: "v"(p), "v"(pk) : "memory");
}

// ---------------------------------------------------------------------------
// Bulk f32 -> bf16 conversion, 8 elements/thread.
__global__ __launch_bounds__(256) void conv_bf16(
    const float* __restrict__ in, short* __restrict__ out, int n8)
{
    const int i = blockIdx.x * 256 + threadIdx.x;
    if (i < n8) {
        const float4 lo = *(const float4*)(in + (size_t)i * 8);
        const float4 hi = *(const float4*)(in + (size_t)i * 8 + 4);
        *(short8*)(out + (size_t)i * 8) = pack8(lo, hi);
    }
}

// ---------------------------------------------------------------------------
// Fold prompt (+bias) into per-layer constant pre-activation vectors.
// pre[0..127]=edge L1, [128..255]=node L1, [256..383]=ae L1, [384..511]=ap L1
__global__ __launch_bounds__(128) void pre_kernel(
    const float* __restrict__ prompt,
    const float* __restrict__ e_w1, const float* __restrict__ e_b1,
    const float* __restrict__ n_w1, const float* __restrict__ n_b1,
    const float* __restrict__ ae_w1, const float* __restrict__ ae_b1,
    const float* __restrict__ ap_w1, const float* __restrict__ ap_b1,
    float* __restrict__ pre)
{
    const int j = threadIdx.x;
    __shared__ float p[HID];
    p[j] = prompt[j];
    __syncthreads();
    float a0 = e_b1[j], a1 = n_b1[j], a2 = ae_b1[j], a3 = ap_b1[j];
    for (int k = 0; k < HID; ++k) {
        const float pk = p[k];
        a0 = fmaf(pk, e_w1[(273 + k) * HID + j], a0);
        a1 = fmaf(pk, n_w1[(256 + k) * HID + j], a1);
        a2 = fmaf(pk, ae_w1[(128 + k) * HID + j], a2);
        a3 = fmaf(pk, ap_w1[(128 + k) * HID + j], a3);
    }
    pre[j] = a0;
    pre[HID + j] = a1;
    pre[2 * HID + j] = a2;
    pre[3 * HID + j] = a3;
}

// ---------------------------------------------------------------------------
// Swizzle all weight matrices into bf16 B-fragment layout:
// frag (kt,nt): element (lane l, i) = W[kt*32 + (l>>4)*8 + i][nt*16 + (l&15)]
// e_w1 K-map: k<256 = h rows, k 256..271 = eattr rows (orig 257..272),
//             k==272 = radial row (orig 256), k 273..287 = zero pad
__global__ __launch_bounds__(64) void prep_weights(
    const float* __restrict__ e_w1, const float* __restrict__ e_w2,
    const float* __restrict__ ae_w1, const float* __restrict__ n_w1,
    const float* __restrict__ n_w2, const float* __restrict__ ap_w1,
    short* __restrict__ wsw)
{
    const int fid = blockIdx.x;
    const int l = threadIdx.x;
    int kt, nt;
    const float* W = nullptr;
    int kmax = 128;
    int e1 = 0;
    if (fid < 72) { kt = fid >> 3; nt = fid & 7; e1 = 1; }
    else if (fid < 104) { int f = fid - 72;  kt = f >> 3; nt = f & 7; W = e_w2; }
    else if (fid < 136) { int f = fid - 104; kt = f >> 3; nt = f & 7; W = ae_w1; }
    else if (fid < 200) { int f = fid - 136; kt = f >> 3; nt = f & 7; W = n_w1; kmax = 256; }
    else if (fid < 232) { int f = fid - 200; kt = f >> 3; nt = f & 7; W = n_w2; }
    else                { int f = fid - 232; kt = f >> 3; nt = f & 7; W = ap_w1; }

    short8 v;
#pragma unroll
    for (int i = 0; i < 8; ++i) {
        const int k = kt * 32 + ((l >> 4) * 8) + i;
        const int n = nt * 16 + (l & 15);
        float f = 0.0f;
        if (e1) {
            if (k < 256) f = e_w1[k * HID + n];
            else if (k < 272) f = e_w1[(k + 1) * HID + n];
            else if (k == 272) f = e_w1[256 * HID + n];
        } else {
            if (k < kmax) f = W[k * HID + n];
        }
        v[i] = f2bf(f);
    }
    *(short8*)&wsw[(size_t)fid * 512 + l * 8] = v;
}

// ---------------------------------------------------------------------------
// P1 = h @ e_w1[0:128], P2 = h @ e_w1[128:256]  (per-node precompute, bf16)
// 64 nodes/block, 2 waves x 32 nodes. Reuses Bw1 frags kt 0..3 / 4..7.
__global__ __launch_bounds__(128, 3) void prep_P(
    const short* __restrict__ hb, const short* __restrict__ Bw1,
    short* __restrict__ P1, short* __restrict__ P2)
{
    const int t = threadIdx.x;
    const int wv = t >> 6, l = t & 63;
    const int lq = l >> 4, lr = l & 15;
    const int n0 = blockIdx.x * 64 + wv * 32;

    short8 A[2][4];
#pragma unroll
    for (int mt = 0; mt < 2; ++mt) {
        int node = n0 + mt * 16 + lr;
        if (node >= NN) node = NN - 1;
#pragma unroll
        for (int kt = 0; kt < 4; ++kt)
            A[mt][kt] = *(const short8*)(hb + (unsigned)node * HID + kt * 32 + lq * 8);
    }
#pragma unroll
    for (int half = 0; half < 2; ++half) {
        short* dst = half ? P2 : P1;
        f32x4 acc[2][8];
#pragma unroll
        for (int tt = 0; tt < 8; ++tt) {
            acc[0][tt] = (f32x4){0.f, 0.f, 0.f, 0.f};
            acc[1][tt] = acc[0][tt];
        }
#pragma unroll
        for (int kt = 0; kt < 4; ++kt) {
#pragma unroll
            for (int tt = 0; tt < 8; ++tt) {
                const short8 b = *(const short8*)&Bw1[(((half * 4 + kt) * 8 + tt) * 64 + l) * 8];
                acc[0][tt] = MFMA(A[0][kt], b, acc[0][tt]);
                acc[1][tt] = MFMA(A[1][kt], b, acc[1][tt]);
            }
        }
#pragma unroll
        for (int mt = 0; mt < 2; ++mt)
#pragma unroll
            for (int tt = 0; tt < 8; ++tt) {
                const int n = tt * 16 + lr;
#pragma unroll
                for (int r = 0; r < 4; ++r) {
                    const int node = n0 + mt * 16 + lq * 4 + r;
                    if (node < NN)
                        dst[(unsigned)node * HID + n] = f2bf(acc[mt][tt][r]);
                }
            }
    }
}

// ---------------------------------------------------------------------------
// Edge pass: 64 edges/block, 2 independent waves x 32 edges (no barriers).
// L1 = silu(P1[row] + P2[col] + (eattr,radial)@W + pre): only 1 K-tile MFMA.
__global__ __launch_bounds__(128, 3) void edge_kernel(
    const short* __restrict__ P1, const short* __restrict__ P2,
    const int* __restrict__ ei, const float* __restrict__ coord,
    const short* __restrict__ eb,
    const short* __restrict__ Bw1, const short* __restrict__ Bw2,
    const short* __restrict__ Bae,
    const float* __restrict__ e_b2, const float* __restrict__ ae_w2,
    const float* __restrict__ pre,
    short* __restrict__ agg, float* __restrict__ agg_c)
{
    const int t = threadIdx.x;
    const int wv = t >> 6, l = t & 63;
    const int lq = l >> 4, lr = l & 15;
    const int e0 = blockIdx.x * 64 + wv * 32;   // this wave's base edge

    __shared__ __align__(16) short s_buf[2][32 * HID];  // 8KB per wave
    char* Hb = (char*)&s_buf[wv][0];

    // --- per-lane edge metadata (lanes 0..31 hold edge me = l) ---
    int r_row = 0, r_col = 0;
    float rad = 0.f, cnx = 0.f, cny = 0.f, cnz = 0.f;
    if (l < 32) {
        const int e = e0 + l;
        r_row = ei[e];
        r_col = ei[NE + e];
        const float dx = coord[r_row * 3 + 0] - coord[r_col * 3 + 0];
        const float dy = coord[r_row * 3 + 1] - coord[r_col * 3 + 1];
        const float dz = coord[r_row * 3 + 2] - coord[r_col * 3 + 2];
        rad = dx * dx + dy * dy + dz * dz;
        const float inv = 1.0f / fmaxf(sqrtf(rad), 1e-12f);
        cnx = dx * inv; cny = dy * inv; cnz = dz * inv;
    }

    // --- issue P1[row]/P2[col] gathers early (A-layout chunks) ---
    short8 p1f[2][4], p2f[2][4];
    short8 Ae[2];
#pragma unroll
    for (int mt = 0; mt < 2; ++mt) {
        const int me = mt * 16 + lr;
        const int srow = __shfl(r_row, me);
        const int scol = __shfl(r_col, me);
        const float radm = __shfl(rad, me);
#pragma unroll
        for (int kt = 0; kt < 4; ++kt) {
            p1f[mt][kt] = *(const short8*)(P1 + (unsigned)srow * HID + kt * 32 + lq * 8);
            p2f[mt][kt] = *(const short8*)(P2 + (unsigned)scol * HID + kt * 32 + lq * 8);
        }
        short8 v = {0, 0, 0, 0, 0, 0, 0, 0};
        if (lq < 2) {
            v = *(const short8*)(eb + (size_t)(e0 + me) * 16 + lq * 8);
        } else if (lq == 2) {
            v[0] = f2bf(radm);
        }
        Ae[mt] = v;
    }

    // --- E term: (eattr,radial) @ W (kt=8 frags) + pre ---
    f32x4 acc[2][8];
#pragma unroll
    for (int tt = 0; tt < 8; ++tt) {
        const float pe = pre[tt * 16 + lr];
        acc[0][tt] = (f32x4){pe, pe, pe, pe};
        acc[1][tt] = acc[0][tt];
    }
#pragma unroll
    for (int tt = 0; tt < 8; ++tt) {
        const short8 b = *(const short8*)&Bw1[((8 * 8 + tt) * 64 + l) * 8];
        acc[0][tt] = MFMA(Ae[0], b, acc[0][tt]);
        acc[1][tt] = MFMA(Ae[1], b, acc[1][tt]);
    }
    // E (pre-activation, bf16) -> swizzled LDS transpose buffer
#pragma unroll
    for (int mt = 0; mt < 2; ++mt)
#pragma unroll
        for (int tt = 0; tt < 8; ++tt) {
            const int n = tt * 16 + lr;
#pragma unroll
            for (int r = 0; r < 4; ++r) {
                const int lm = mt * 16 + lq * 4 + r;
                const int off = (lm * 256 + n * 2) ^ ((lm & 7) << 4);
                *(short*)(Hb + off) = f2bf(acc[mt][tt][r]);
            }
        }
    asm volatile("s_waitcnt lgkmcnt(0)" ::: "memory");

    // --- A2 = silu(E + P1 + P2) in A-layout ---
    short8 A2[2][4];
#pragma unroll
    for (int mt = 0; mt < 2; ++mt) {
        const int lm = mt * 16 + lr;
        const int sw = (lm & 7) << 4;
#pragma unroll
        for (int kt = 0; kt < 4; ++kt) {
            const short8 e = *(const short8*)(Hb + ((lm * 256 + kt * 64 + lq * 16) ^ sw));
            A2[mt][kt] = fuse_silu(e, p1f[mt][kt], p2f[mt][kt]);
        }
    }

    // --- layer 2: K = 128 ---
    f32x4 acc2[2][8];
#pragma unroll
    for (int tt = 0; tt < 8; ++tt) {
        const float b2 = e_b2[tt * 16 + lr];
        acc2[0][tt] = (f32x4){b2, b2, b2, b2};
        acc2[1][tt] = acc2[0][tt];
    }
#pragma unroll
    for (int kt = 0; kt < 4; ++kt) {
#pragma unroll
        for (int tt = 0; tt < 8; ++tt) {
            const short8 b = *(const short8*)&Bw2[((kt * 8 + tt) * 64 + l) * 8];
            acc2[0][tt] = MFMA(A2[0][kt], b, acc2[0][tt]);
            acc2[1][tt] = MFMA(A2[1][kt], b, acc2[1][tt]);
        }
    }

    // rows for this lane's C/D positions
    int rowr[2][4];
#pragma unroll
    for (int mt = 0; mt < 2; ++mt)
#pragma unroll
        for (int r = 0; r < 4; ++r)
            rowr[mt][r] = __shfl(r_row, mt * 16 + lq * 4 + r);

    // epilogue: ef = silu -> packed-bf16 atomic agg + swizzled LDS
#pragma unroll
    for (int mt = 0; mt < 2; ++mt)
#pragma unroll
        for (int tt = 0; tt < 8; ++tt) {
            const int n = tt * 16 + lr;
#pragma unroll
            for (int r = 0; r < 4; ++r) {
                const float v = silu_(acc2[mt][tt][r]);
                const int lm = mt * 16 + lq * 4 + r;
                const int off = (lm * 256 + n * 2) ^ ((lm & 7) << 4);
                const short vb = f2bf(v);
                *(short*)(Hb + off) = vb;
                // pair adjacent cols (lr, lr^1) -> one packed atomic on even lr
                const float vn = __shfl_xor(v, 1, 64);
                if ((lr & 1) == 0) {
                    const unsigned pk = (unsigned)(unsigned short)vb |
                                        ((unsigned)(unsigned short)f2bf(vn) << 16);
                    atom_pk_bf16(agg + (unsigned)rowr[mt][r] * HID + n, pk);
                }
            }
        }
    asm volatile("s_waitcnt lgkmcnt(0)" ::: "memory");

    // --- AE layer: K = 128, then dot with ae_w2 ---
    short8 A3[2][4];
#pragma unroll
    for (int mt = 0; mt < 2; ++mt) {
        const int lm = mt * 16 + lr;
        const int sw = (lm & 7) << 4;
#pragma unroll
        for (int kt = 0; kt < 4; ++kt)
            A3[mt][kt] = *(const short8*)(Hb + ((lm * 256 + kt * 64 + lq * 16) ^ sw));
    }
    f32x4 acc3[2][8];
#pragma unroll
    for (int tt = 0; tt < 8; ++tt) {
        const float pa = pre[2 * HID + tt * 16 + lr];
        acc3[0][tt] = (f32x4){pa, pa, pa, pa};
        acc3[1][tt] = acc3[0][tt];
    }
#pragma unroll
    for (int kt = 0; kt < 4; ++kt) {
#pragma unroll
        for (int tt = 0; tt < 8; ++tt) {
            const short8 b = *(const short8*)&Bae[((kt * 8 + tt) * 64 + l) * 8];
            acc3[0][tt] = MFMA(A3[0][kt], b, acc3[0][tt]);
            acc3[1][tt] = MFMA(A3[1][kt], b, acc3[1][tt]);
        }
    }
    float w2v[8];
#pragma unroll
    for (int tt = 0; tt < 8; ++tt) w2v[tt] = ae_w2[tt * 16 + lr];

#pragma unroll
    for (int mt = 0; mt < 2; ++mt) {
        float p0 = 0.f, p1 = 0.f, p2 = 0.f, p3 = 0.f;
#pragma unroll
        for (int tt = 0; tt < 8; ++tt) {
            p0 += silu_(acc3[mt][tt][0]) * w2v[tt];
            p1 += silu_(acc3[mt][tt][1]) * w2v[tt];
            p2 += silu_(acc3[mt][tt][2]) * w2v[tt];
            p3 += silu_(acc3[mt][tt][3]) * w2v[tt];
        }
#pragma unroll
        for (int r = 0; r < 4; ++r) {
            float s = (r == 0) ? p0 : (r == 1) ? p1 : (r == 2) ? p2 : p3;
            s += __shfl_xor(s, 1, 16);
            s += __shfl_xor(s, 2, 16);
            s += __shfl_xor(s, 4, 16);
            s += __shfl_xor(s, 8, 16);
            const int lm = mt * 16 + lq * 4 + r;
            const float sx = __shfl(cnx, lm);
            const float sy = __shfl(cny, lm);
            const float sz = __shfl(cnz, lm);
            if (lr < 3) {
                const float cv = (lr == 0) ? sx : (lr == 1) ? sy : sz;
                atomicAdd(&agg_c[(unsigned)rowr[mt][r] * 3 + lr], cv * s);
            }
        }
    }
}

// ---------------------------------------------------------------------------
// Node pass: 64 nodes/block, 2 independent waves x 32 nodes.
// h A-frags from pre-converted hb; agg bf16 in d_ws.
__global__ __launch_bounds__(128, 3) void node_kernel(
    const float* __restrict__ h, const short* __restrict__ hb,
    const float* __restrict__ coord,
    const short* __restrict__ Bn1, const short* __restrict__ Bn2,
    const short* __restrict__ Bap,
    const float* __restrict__ n_b2, const float* __restrict__ ap_w2,
    const float* __restrict__ pre,
    const short* __restrict__ agg,
    const float* __restrict__ agg_c,
    float* __restrict__ out_h, float* __restrict__ out_coord,
    float* __restrict__ out_acc)
{
    const int t = threadIdx.x;
    const int wv = t >> 6, l = t & 63;
    const int lq = l >> 4, lr = l & 15;
    const int n0 = blockIdx.x * 64 + wv * 32;

    __shared__ __align__(16) short s_buf[2][32 * HID];
    char* Hb = (char*)&s_buf[wv][0];

    // --- A-frags: X = [h | agg], K = 256 ---
    short8 A[2][8];
#pragma unroll
    for (int mt = 0; mt < 2; ++mt) {
        int node = n0 + mt * 16 + lr;
        if (node >= NN) node = NN - 1;
#pragma unroll
        for (int kt = 0; kt < 4; ++kt)
            A[mt][kt] = *(const short8*)(hb + (unsigned)node * HID + kt * 32 + lq * 8);
#pragma unroll
        for (int kt = 4; kt < 8; ++kt)
            A[mt][kt] = *(const short8*)(agg + (unsigned)node * HID + (kt - 4) * 32 + lq * 8);
    }

    // --- layer 1: K = 256 ---
    f32x4 acc[2][8];
#pragma unroll
    for (int tt = 0; tt < 8; ++tt) {
        const float pn = pre[HID + tt * 16 + lr];
        acc[0][tt] = (f32x4){pn, pn, pn, pn};
        acc[1][tt] = acc[0][tt];
    }
#pragma unroll
    for (int kt = 0; kt < 8; ++kt) {
#pragma unroll
        for (int tt = 0; tt < 8; ++tt) {
            const short8 b = *(const short8*)&Bn1[((kt * 8 + tt) * 64 + l) * 8];
            acc[0][tt] = MFMA(A[0][kt], b, acc[0][tt]);
            acc[1][tt] = MFMA(A[1][kt], b, acc[1][tt]);
        }
    }
#pragma unroll
    for (int mt = 0; mt < 2; ++mt)
#pragma unroll
        for (int tt = 0; tt < 8; ++tt) {
            const int n = tt * 16 + lr;
#pragma unroll
            for (int r = 0; r < 4; ++r) {
                const int lm = mt * 16 + lq * 4 + r;
                const int off = (lm * 256 + n * 2) ^ ((lm & 7) << 4);
                *(short*)(Hb + off) = f2bf(silu_(acc[mt][tt][r]));
            }
        }
    asm volatile("s_waitcnt lgkmcnt(0)" ::: "memory");

    // --- layer 2 + residual ---
    short8 A2[2][4];
#pragma unroll
    for (int mt = 0; mt < 2; ++mt) {
        const int lm = mt * 16 + lr;
        const int sw = (lm & 7) << 4;
#pragma unroll
        for (int kt = 0; kt < 4; ++kt)
            A2[mt][kt] = *(const short8*)(Hb + ((lm * 256 + kt * 64 + lq * 16) ^ sw));
    }
    f32x4 acc2[2][8];
#pragma unroll
    for (int tt = 0; tt < 8; ++tt) {
        const float b2 = n_b2[tt * 16 + lr];
        acc2[0][tt] = (f32x4){b2, b2, b2, b2};
        acc2[1][tt] = acc2[0][tt];
    }
#pragma unroll
    for (int kt = 0; kt < 4; ++kt) {
#pragma unroll
        for (int tt = 0; tt < 8; ++tt) {
            const short8 b = *(const short8*)&Bn2[((kt * 8 + tt) * 64 + l) * 8];
            acc2[0][tt] = MFMA(A2[0][kt], b, acc2[0][tt]);
            acc2[1][tt] = MFMA(A2[1][kt], b, acc2[1][tt]);
        }
    }
#pragma unroll
    for (int mt = 0; mt < 2; ++mt)
#pragma unroll
        for (int tt = 0; tt < 8; ++tt) {
            const int n = tt * 16 + lr;
#pragma unroll
            for (int r = 0; r < 4; ++r) {
                const int lm = mt * 16 + lq * 4 + r;
                const int nd = n0 + lm;
                const unsigned ndc = (nd < NN) ? nd : (NN - 1);
                const float hv = h[ndc * HID + n];
                const float ho = hv + silu_(acc2[mt][tt][r]);
                if (nd < NN) out_h[(unsigned)nd * HID + n] = ho;
                const int off = (lm * 256 + n * 2) ^ ((lm & 7) << 4);
                *(short*)(Hb + off) = f2bf(ho);
            }
        }
    asm volatile("s_waitcnt lgkmcnt(0)" ::: "memory");

    // --- AP layer ---
    short8 A3[2][4];
#pragma unroll
    for (int mt = 0; mt < 2; ++mt) {
        const int lm = mt * 16 + lr;
        const int sw = (lm & 7) << 4;
#pragma unroll
        for (int kt = 0; kt < 4; ++kt)
            A3[mt][kt] = *(const short8*)(Hb + ((lm * 256 + kt * 64 + lq * 16) ^ sw));
    }
    f32x4 acc3[2][8];
#pragma unroll
    for (int tt = 0; tt < 8; ++tt) {
        const float pa = pre[3 * HID + tt * 16 + lr];
        acc3[0][tt] = (f32x4){pa, pa, pa, pa};
        acc3[1][tt] = acc3[0][tt];
    }
#pragma unroll
    for (int kt = 0; kt < 4; ++kt) {
#pragma unroll
        for (int tt = 0; tt < 8; ++tt) {
            const short8 b = *(const short8*)&Bap[((kt * 8 + tt) * 64 + l) * 8];
            acc3[0][tt] = MFMA(A3[0][kt], b, acc3[0][tt]);
            acc3[1][tt] = MFMA(A3[1][kt], b, acc3[1][tt]);
        }
    }
    float w2v[8];
#pragma unroll
    for (int tt = 0; tt < 8; ++tt) w2v[tt] = ap_w2[tt * 16 + lr];

#pragma unroll
    for (int mt = 0; mt < 2; ++mt) {
        float p0 = 0.f, p1 = 0.f, p2 = 0.f, p3 = 0.f;
#pragma unroll
        for (int tt = 0; tt < 8; ++tt) {
            p0 += silu_(acc3[mt][tt][0]) * w2v[tt];
            p1 += silu_(acc3[mt][tt][1]) * w2v[tt];
            p2 += silu_(acc3[mt][tt][2]) * w2v[tt];
            p3 += silu_(acc3[mt][tt][3]) * w2v[tt];
        }
#pragma unroll
        for (int r = 0; r < 4; ++r) {
            float s = (r == 0) ? p0 : (r == 1) ? p1 : (r == 2) ? p2 : p3;
            s += __shfl_xor(s, 1, 16);
            s += __shfl_xor(s, 2, 16);
            s += __shfl_xor(s, 4, 16);
            s += __shfl_xor(s, 8, 16);
            const int lm = mt * 16 + lq * 4 + r;
            const int nd = n0 + lm;
            if (lr < 3 && nd < NN) {
                out_acc[(unsigned)nd * 3 + lr] = agg_c[(unsigned)nd * 3 + lr] * s;
                out_coord[(unsigned)nd * 3 + lr] = coord[(unsigned)nd * 3 + lr];
            }
        }
    }
}

// ---------------------------------------------------------------------------
extern "C" void kernel_launch(void* const* d_in, const int* in_sizes, int n_in,
                              void* d_out, int out_size, void* d_ws, size_t ws_size,
                              hipStream_t stream)
{
    const float* h      = (const float*)d_in[0];
    const int*   ei     = (const int*)d_in[1];
    const float* coord  = (const float*)d_in[2];
    const float* eattr  = (const float*)d_in[3];
    const float* prompt = (const float*)d_in[4];
    const float* e_w1 = (const float*)d_in[5];
    const float* e_b1 = (const float*)d_in[6];
    const float* e_w2 = (const float*)d_in[7];
    const float* e_b2 = (const float*)d_in[8];
    const float* n_w1 = (const float*)d_in[9];
    const float* n_b1 = (const float*)d_in[10];
    const float* n_w2 = (const float*)d_in[11];
    const float* n_b2 = (const float*)d_in[12];
    const float* ae_w1 = (const float*)d_in[13];
    const float* ae_b1 = (const float*)d_in[14];
    const float* ae_w2 = (const float*)d_in[15];
    const float* ap_w1 = (const float*)d_in[16];
    const float* ap_b1 = (const float*)d_in[17];
    const float* ap_w2 = (const float*)d_in[18];

    float* out       = (float*)d_out;
    float* out_h     = out;                          // [NN,128]
    float* out_coord = out + (size_t)NN * HID;       // [NN,3]
    float* out_acc   = out_coord + (size_t)NN * 3;   // [NN,3]

    float* agg_c = (float*)d_ws;                     // [NN,3] f32
    float* pre   = agg_c + (size_t)NN * 3;           // [512]
    short* wsw   = (short*)(pre + 512);              // 264 frags x 512 shorts
    short* aggb  = wsw + 264 * 512;                  // [NN,128] bf16 agg
    short* hb    = aggb + (size_t)NN * HID;          // [NN,128] bf16 h
    short* P1    = hb + (size_t)NN * HID;            // [NN,128] bf16
    short* P2    = P1 + (size_t)NN * HID;            // [NN,128] bf16

    // eattr bf16 [NE,16] = 25.6MB: overlaid on out_h region (only needed
    // during edge pass; out_h is written exclusively by node_kernel later)
    short* eb = (short*)out_h;

    const short* Bw1 = wsw;            // e_w1: 72 frags
    const short* Bw2 = wsw + 36864;    // e_w2: 32
    const short* Bae = wsw + 53248;    // ae_w1: 32
    const short* Bn1 = wsw + 69632;    // n_w1: 64
    const short* Bn2 = wsw + 102400;   // n_w2: 32
    const short* Bap = wsw + 118784;   // ap_w1: 32

    hipMemsetAsync(aggb, 0, (size_t)NN * HID * sizeof(short), stream);
    hipMemsetAsync(agg_c, 0, (size_t)NN * 3 * sizeof(float), stream);

    pre_kernel<<<1, 128, 0, stream>>>(prompt, e_w1, e_b1, n_w1, n_b1,
                                      ae_w1, ae_b1, ap_w1, ap_b1, pre);
    prep_weights<<<264, 64, 0, stream>>>(e_w1, e_w2, ae_w1, n_w1, n_w2, ap_w1, wsw);
    conv_bf16<<<(NN * HID / 8 + 255) / 256, 256, 0, stream>>>(h, hb, NN * HID / 8);
    conv_bf16<<<(NE * 16 / 8 + 255) / 256, 256, 0, stream>>>(eattr, eb, NE * 16 / 8);
    prep_P<<<(NN + 63) / 64, 128, 0, stream>>>(hb, Bw1, P1, P2);

    edge_kernel<<<NE / 64, 128, 0, stream>>>(P1, P2, ei, coord, eb,
                                             Bw1, Bw2, Bae, e_b2, ae_w2,
                                             pre, aggb, agg_c);
    node_kernel<<<(NN + 63) / 64, 128, 0, stream>>>(h, hb, coord, Bn1, Bn2, Bap,
                                                    n_b2, ap_w2, pre,
                                                    aggb, agg_c,
                                                    out_h, out_coord, out_acc);
}

// Round 11
// 648.657 us; speedup vs baseline: 1.2749x; 1.2749x over previous
//
#include <hip/hip_runtime.h>
#include <math.h>

#define NN 50000
#define NE 800000
#define HID 128

typedef __attribute__((ext_vector_type(8))) short short8;
typedef __attribute__((ext_vector_type(4))) float f32x4;

#define MFMA(a, b, c) __builtin_amdgcn_mfma_f32_16x16x32_bf16(a, b, c, 0, 0, 0)

// fast silu: x * rcp(1+exp(-x)); v_rcp_f32 ~1ulp, negligible vs bf16 rounding
__device__ __forceinline__ float silu_(float x) {
    return x * __builtin_amdgcn_rcpf(1.0f + __expf(-x));
}

__device__ __forceinline__ float bf2f(short x) {
    union { unsigned u; float f; } v;
    v.u = ((unsigned)(unsigned short)x) << 16;
    return v.f;
}

// f32 -> bf16 bits, round-to-nearest-even
__device__ __forceinline__ short f2bf(float f) {
    union { float f; unsigned u; } v;
    v.f = f;
    unsigned r = v.u + 0x7fffu + ((v.u >> 16) & 1u);
    return (short)(r >> 16);
}

__device__ __forceinline__ short8 pack8(float4 lo, float4 hi) {
    short8 v;
    v[0] = f2bf(lo.x); v[1] = f2bf(lo.y); v[2] = f2bf(lo.z); v[3] = f2bf(lo.w);
    v[4] = f2bf(hi.x); v[5] = f2bf(hi.y); v[6] = f2bf(hi.z); v[7] = f2bf(hi.w);
    return v;
}

// L1 fuse: silu(E + P1 + P2) elementwise on bf16 octets
__device__ __forceinline__ short8 fuse_silu(short8 e, short8 p1, short8 p2) {
    short8 o;
#pragma unroll
    for (int i = 0; i < 8; ++i)
        o[i] = f2bf(silu_(bf2f(e[i]) + bf2f(p1[i]) + bf2f(p2[i])));
    return o;
}

// packed bf16 atomic add: adds 2 bf16 lanes at *p (4B aligned)
__device__ __forceinline__ void atom_pk_bf16(short* p, unsigned pk) {
    asm volatile("global_atomic_pk_add_bf16 %0, %1, off"
                 :: "v"(p), "v"(pk) : "memory");
}

// ---------------------------------------------------------------------------
// Bulk f32 -> bf16 conversion, 8 elements/thread.
__global__ __launch_bounds__(256) void conv_bf16(
    const float* __restrict__ in, short* __restrict__ out, int n8)
{
    const int i = blockIdx.x * 256 + threadIdx.x;
    if (i < n8) {
        const float4 lo = *(const float4*)(in + (size_t)i * 8);
        const float4 hi = *(const float4*)(in + (size_t)i * 8 + 4);
        *(short8*)(out + (size_t)i * 8) = pack8(lo, hi);
    }
}

// ---------------------------------------------------------------------------
// Fold prompt (+bias) into per-layer constant pre-activation vectors.
// pre[0..127]=edge L1, [128..255]=node L1, [256..383]=ae L1, [384..511]=ap L1
__global__ __launch_bounds__(128) void pre_kernel(
    const float* __restrict__ prompt,
    const float* __restrict__ e_w1, const float* __restrict__ e_b1,
    const float* __restrict__ n_w1, const float* __restrict__ n_b1,
    const float* __restrict__ ae_w1, const float* __restrict__ ae_b1,
    const float* __restrict__ ap_w1, const float* __restrict__ ap_b1,
    float* __restrict__ pre)
{
    const int j = threadIdx.x;
    __shared__ float p[HID];
    p[j] = prompt[j];
    __syncthreads();
    float a0 = e_b1[j], a1 = n_b1[j], a2 = ae_b1[j], a3 = ap_b1[j];
    for (int k = 0; k < HID; ++k) {
        const float pk = p[k];
        a0 = fmaf(pk, e_w1[(273 + k) * HID + j], a0);
        a1 = fmaf(pk, n_w1[(256 + k) * HID + j], a1);
        a2 = fmaf(pk, ae_w1[(128 + k) * HID + j], a2);
        a3 = fmaf(pk, ap_w1[(128 + k) * HID + j], a3);
    }
    pre[j] = a0;
    pre[HID + j] = a1;
    pre[2 * HID + j] = a2;
    pre[3 * HID + j] = a3;
}

// ---------------------------------------------------------------------------
// Swizzle all weight matrices into bf16 B-fragment layout:
// frag (kt,nt): element (lane l, i) = W[kt*32 + (l>>4)*8 + i][nt*16 + (l&15)]
// e_w1 K-map: k<256 = h rows, k 256..271 = eattr rows (orig 257..272),
//             k==272 = radial row (orig 256), k 273..287 = zero pad
__global__ __launch_bounds__(64) void prep_weights(
    const float* __restrict__ e_w1, const float* __restrict__ e_w2,
    const float* __restrict__ ae_w1, const float* __restrict__ n_w1,
    const float* __restrict__ n_w2, const float* __restrict__ ap_w1,
    short* __restrict__ wsw)
{
    const int fid = blockIdx.x;
    const int l = threadIdx.x;
    int kt, nt;
    const float* W = nullptr;
    int kmax = 128;
    int e1 = 0;
    if (fid < 72) { kt = fid >> 3; nt = fid & 7; e1 = 1; }
    else if (fid < 104) { int f = fid - 72;  kt = f >> 3; nt = f & 7; W = e_w2; }
    else if (fid < 136) { int f = fid - 104; kt = f >> 3; nt = f & 7; W = ae_w1; }
    else if (fid < 200) { int f = fid - 136; kt = f >> 3; nt = f & 7; W = n_w1; kmax = 256; }
    else if (fid < 232) { int f = fid - 200; kt = f >> 3; nt = f & 7; W = n_w2; }
    else                { int f = fid - 232; kt = f >> 3; nt = f & 7; W = ap_w1; }

    short8 v;
#pragma unroll
    for (int i = 0; i < 8; ++i) {
        const int k = kt * 32 + ((l >> 4) * 8) + i;
        const int n = nt * 16 + (l & 15);
        float f = 0.0f;
        if (e1) {
            if (k < 256) f = e_w1[k * HID + n];
            else if (k < 272) f = e_w1[(k + 1) * HID + n];
            else if (k == 272) f = e_w1[256 * HID + n];
        } else {
            if (k < kmax) f = W[k * HID + n];
        }
        v[i] = f2bf(f);
    }
    *(short8*)&wsw[(size_t)fid * 512 + l * 8] = v;
}

// ---------------------------------------------------------------------------
// P1 = h @ e_w1[0:128], P2 = h @ e_w1[128:256]  (per-node precompute, bf16)
// 64 nodes/block, 2 waves x 32 nodes. Reuses Bw1 frags kt 0..3 / 4..7.
__global__ __launch_bounds__(128, 3) void prep_P(
    const short* __restrict__ hb, const short* __restrict__ Bw1,
    short* __restrict__ P1, short* __restrict__ P2)
{
    const int t = threadIdx.x;
    const int wv = t >> 6, l = t & 63;
    const int lq = l >> 4, lr = l & 15;
    const int n0 = blockIdx.x * 64 + wv * 32;

    short8 A[2][4];
#pragma unroll
    for (int mt = 0; mt < 2; ++mt) {
        int node = n0 + mt * 16 + lr;
        if (node >= NN) node = NN - 1;
#pragma unroll
        for (int kt = 0; kt < 4; ++kt)
            A[mt][kt] = *(const short8*)(hb + (unsigned)node * HID + kt * 32 + lq * 8);
    }
#pragma unroll
    for (int half = 0; half < 2; ++half) {
        short* dst = half ? P2 : P1;
        f32x4 acc[2][8];
#pragma unroll
        for (int tt = 0; tt < 8; ++tt) {
            acc[0][tt] = (f32x4){0.f, 0.f, 0.f, 0.f};
            acc[1][tt] = acc[0][tt];
        }
#pragma unroll
        for (int kt = 0; kt < 4; ++kt) {
#pragma unroll
            for (int tt = 0; tt < 8; ++tt) {
                const short8 b = *(const short8*)&Bw1[(((half * 4 + kt) * 8 + tt) * 64 + l) * 8];
                acc[0][tt] = MFMA(A[0][kt], b, acc[0][tt]);
                acc[1][tt] = MFMA(A[1][kt], b, acc[1][tt]);
            }
        }
#pragma unroll
        for (int mt = 0; mt < 2; ++mt)
#pragma unroll
            for (int tt = 0; tt < 8; ++tt) {
                const int n = tt * 16 + lr;
#pragma unroll
                for (int r = 0; r < 4; ++r) {
                    const int node = n0 + mt * 16 + lq * 4 + r;
                    if (node < NN)
                        dst[(unsigned)node * HID + n] = f2bf(acc[mt][tt][r]);
                }
            }
    }
}

// ---------------------------------------------------------------------------
// Edge pass: 32 edges/block, 2 independent waves x 16 edges (no barriers).
// Small per-wave tile -> ~100 regs -> 4 waves/SIMD for latency hiding.
__global__ __launch_bounds__(128, 4) void edge_kernel(
    const short* __restrict__ P1, const short* __restrict__ P2,
    const int* __restrict__ ei, const float* __restrict__ coord,
    const short* __restrict__ eb,
    const short* __restrict__ Bw1, const short* __restrict__ Bw2,
    const short* __restrict__ Bae,
    const float* __restrict__ e_b2, const float* __restrict__ ae_w2,
    const float* __restrict__ pre,
    short* __restrict__ agg, float* __restrict__ agg_c)
{
    const int t = threadIdx.x;
    const int wv = t >> 6, l = t & 63;
    const int lq = l >> 4, lr = l & 15;
    const int e0 = blockIdx.x * 32 + wv * 16;   // this wave's base edge

    __shared__ __align__(16) short s_buf[2][16 * HID];  // 4KB per wave
    char* Hb = (char*)&s_buf[wv][0];

    // --- per-lane edge metadata (lanes 0..15 hold edge = l) ---
    int r_row = 0, r_col = 0;
    float rad = 0.f, cnx = 0.f, cny = 0.f, cnz = 0.f;
    if (l < 16) {
        const int e = e0 + l;
        r_row = ei[e];
        r_col = ei[NE + e];
        const float dx = coord[r_row * 3 + 0] - coord[r_col * 3 + 0];
        const float dy = coord[r_row * 3 + 1] - coord[r_col * 3 + 1];
        const float dz = coord[r_row * 3 + 2] - coord[r_col * 3 + 2];
        rad = dx * dx + dy * dy + dz * dz;
        const float inv = 1.0f / fmaxf(sqrtf(rad), 1e-12f);
        cnx = dx * inv; cny = dy * inv; cnz = dz * inv;
    }
    const int srow = __shfl(r_row, lr);
    const int scol = __shfl(r_col, lr);
    const float radm = __shfl(rad, lr);

    // --- P1[row]/P2[col] gathers (A-layout chunks) + eattr/radial tile ---
    short8 p1f[4], p2f[4];
#pragma unroll
    for (int kt = 0; kt < 4; ++kt) {
        p1f[kt] = *(const short8*)(P1 + (unsigned)srow * HID + kt * 32 + lq * 8);
        p2f[kt] = *(const short8*)(P2 + (unsigned)scol * HID + kt * 32 + lq * 8);
    }
    short8 Ae = {0, 0, 0, 0, 0, 0, 0, 0};
    if (lq < 2) {
        Ae = *(const short8*)(eb + (size_t)(e0 + lr) * 16 + lq * 8);
    } else if (lq == 2) {
        Ae[0] = f2bf(radm);
    }

    // --- E term: (eattr,radial) @ W (kt=8 frags) + pre ---
    f32x4 acc[8];
#pragma unroll
    for (int tt = 0; tt < 8; ++tt) {
        const float pe = pre[tt * 16 + lr];
        acc[tt] = (f32x4){pe, pe, pe, pe};
    }
#pragma unroll
    for (int tt = 0; tt < 8; ++tt) {
        const short8 b = *(const short8*)&Bw1[((8 * 8 + tt) * 64 + l) * 8];
        acc[tt] = MFMA(Ae, b, acc[tt]);
    }
    // E (pre-activation, bf16) -> swizzled LDS transpose buffer
#pragma unroll
    for (int tt = 0; tt < 8; ++tt) {
        const int n = tt * 16 + lr;
#pragma unroll
        for (int r = 0; r < 4; ++r) {
            const int m = lq * 4 + r;
            const int off = (m * 256 + n * 2) ^ ((m & 7) << 4);
            *(short*)(Hb + off) = f2bf(acc[tt][r]);
        }
    }
    asm volatile("s_waitcnt lgkmcnt(0)" ::: "memory");

    // --- A2 = silu(E + P1 + P2) in A-layout ---
    short8 A2[4];
    {
        const int sw = (lr & 7) << 4;
#pragma unroll
        for (int kt = 0; kt < 4; ++kt) {
            const short8 e = *(const short8*)(Hb + ((lr * 256 + kt * 64 + lq * 16) ^ sw));
            A2[kt] = fuse_silu(e, p1f[kt], p2f[kt]);
        }
    }

    // --- layer 2: K = 128 ---
    f32x4 acc2[8];
#pragma unroll
    for (int tt = 0; tt < 8; ++tt) {
        const float b2 = e_b2[tt * 16 + lr];
        acc2[tt] = (f32x4){b2, b2, b2, b2};
    }
#pragma unroll
    for (int kt = 0; kt < 4; ++kt) {
#pragma unroll
        for (int tt = 0; tt < 8; ++tt) {
            const short8 b = *(const short8*)&Bw2[((kt * 8 + tt) * 64 + l) * 8];
            acc2[tt] = MFMA(A2[kt], b, acc2[tt]);
        }
    }

    // rows for this lane's C/D positions
    int rowr[4];
#pragma unroll
    for (int r = 0; r < 4; ++r)
        rowr[r] = __shfl(r_row, lq * 4 + r);

    // epilogue: ef = silu -> packed-bf16 atomic agg + swizzled LDS
#pragma unroll
    for (int tt = 0; tt < 8; ++tt) {
        const int n = tt * 16 + lr;
#pragma unroll
        for (int r = 0; r < 4; ++r) {
            const float v = silu_(acc2[tt][r]);
            const int m = lq * 4 + r;
            const int off = (m * 256 + n * 2) ^ ((m & 7) << 4);
            const short vb = f2bf(v);
            *(short*)(Hb + off) = vb;
            // pair adjacent cols (lr, lr^1) -> one packed atomic on even lr
            const float vn = __shfl_xor(v, 1, 64);
            if ((lr & 1) == 0) {
                const unsigned pk = (unsigned)(unsigned short)vb |
                                    ((unsigned)(unsigned short)f2bf(vn) << 16);
                atom_pk_bf16(agg + (unsigned)rowr[r] * HID + n, pk);
            }
        }
    }
    asm volatile("s_waitcnt lgkmcnt(0)" ::: "memory");

    // --- AE layer: K = 128, then dot with ae_w2 ---
    short8 A3[4];
    {
        const int sw = (lr & 7) << 4;
#pragma unroll
        for (int kt = 0; kt < 4; ++kt)
            A3[kt] = *(const short8*)(Hb + ((lr * 256 + kt * 64 + lq * 16) ^ sw));
    }
    f32x4 acc3[8];
#pragma unroll
    for (int tt = 0; tt < 8; ++tt) {
        const float pa = pre[2 * HID + tt * 16 + lr];
        acc3[tt] = (f32x4){pa, pa, pa, pa};
    }
#pragma unroll
    for (int kt = 0; kt < 4; ++kt) {
#pragma unroll
        for (int tt = 0; tt < 8; ++tt) {
            const short8 b = *(const short8*)&Bae[((kt * 8 + tt) * 64 + l) * 8];
            acc3[tt] = MFMA(A3[kt], b, acc3[tt]);
        }
    }
    float w2v[8];
#pragma unroll
    for (int tt = 0; tt < 8; ++tt) w2v[tt] = ae_w2[tt * 16 + lr];

    {
        float p0 = 0.f, p1 = 0.f, p2 = 0.f, p3 = 0.f;
#pragma unroll
        for (int tt = 0; tt < 8; ++tt) {
            p0 += silu_(acc3[tt][0]) * w2v[tt];
            p1 += silu_(acc3[tt][1]) * w2v[tt];
            p2 += silu_(acc3[tt][2]) * w2v[tt];
            p3 += silu_(acc3[tt][3]) * w2v[tt];
        }
#pragma unroll
        for (int r = 0; r < 4; ++r) {
            float s = (r == 0) ? p0 : (r == 1) ? p1 : (r == 2) ? p2 : p3;
            s += __shfl_xor(s, 1, 16);
            s += __shfl_xor(s, 2, 16);
            s += __shfl_xor(s, 4, 16);
            s += __shfl_xor(s, 8, 16);
            const int m = lq * 4 + r;
            const float sx = __shfl(cnx, m);
            const float sy = __shfl(cny, m);
            const float sz = __shfl(cnz, m);
            if (lr < 3) {
                const float cv = (lr == 0) ? sx : (lr == 1) ? sy : sz;
                atomicAdd(&agg_c[(unsigned)rowr[r] * 3 + lr], cv * s);
            }
        }
    }
}

// ---------------------------------------------------------------------------
// Node pass: 64 nodes/block, 2 independent waves x 32 nodes.
// h A-frags from pre-converted hb; agg bf16 in d_ws.
__global__ __launch_bounds__(128, 3) void node_kernel(
    const float* __restrict__ h, const short* __restrict__ hb,
    const float* __restrict__ coord,
    const short* __restrict__ Bn1, const short* __restrict__ Bn2,
    const short* __restrict__ Bap,
    const float* __restrict__ n_b2, const float* __restrict__ ap_w2,
    const float* __restrict__ pre,
    const short* __restrict__ agg,
    const float* __restrict__ agg_c,
    float* __restrict__ out_h, float* __restrict__ out_coord,
    float* __restrict__ out_acc)
{
    const int t = threadIdx.x;
    const int wv = t >> 6, l = t & 63;
    const int lq = l >> 4, lr = l & 15;
    const int n0 = blockIdx.x * 64 + wv * 32;

    __shared__ __align__(16) short s_buf[2][32 * HID];
    char* Hb = (char*)&s_buf[wv][0];

    // --- A-frags: X = [h | agg], K = 256 ---
    short8 A[2][8];
#pragma unroll
    for (int mt = 0; mt < 2; ++mt) {
        int node = n0 + mt * 16 + lr;
        if (node >= NN) node = NN - 1;
#pragma unroll
        for (int kt = 0; kt < 4; ++kt)
            A[mt][kt] = *(const short8*)(hb + (unsigned)node * HID + kt * 32 + lq * 8);
#pragma unroll
        for (int kt = 4; kt < 8; ++kt)
            A[mt][kt] = *(const short8*)(agg + (unsigned)node * HID + (kt - 4) * 32 + lq * 8);
    }

    // --- layer 1: K = 256 ---
    f32x4 acc[2][8];
#pragma unroll
    for (int tt = 0; tt < 8; ++tt) {
        const float pn = pre[HID + tt * 16 + lr];
        acc[0][tt] = (f32x4){pn, pn, pn, pn};
        acc[1][tt] = acc[0][tt];
    }
#pragma unroll
    for (int kt = 0; kt < 8; ++kt) {
#pragma unroll
        for (int tt = 0; tt < 8; ++tt) {
            const short8 b = *(const short8*)&Bn1[((kt * 8 + tt) * 64 + l) * 8];
            acc[0][tt] = MFMA(A[0][kt], b, acc[0][tt]);
            acc[1][tt] = MFMA(A[1][kt], b, acc[1][tt]);
        }
    }
#pragma unroll
    for (int mt = 0; mt < 2; ++mt)
#pragma unroll
        for (int tt = 0; tt < 8; ++tt) {
            const int n = tt * 16 + lr;
#pragma unroll
            for (int r = 0; r < 4; ++r) {
                const int lm = mt * 16 + lq * 4 + r;
                const int off = (lm * 256 + n * 2) ^ ((lm & 7) << 4);
                *(short*)(Hb + off) = f2bf(silu_(acc[mt][tt][r]));
            }
        }
    asm volatile("s_waitcnt lgkmcnt(0)" ::: "memory");

    // --- layer 2 + residual ---
    short8 A2[2][4];
#pragma unroll
    for (int mt = 0; mt < 2; ++mt) {
        const int lm = mt * 16 + lr;
        const int sw = (lm & 7) << 4;
#pragma unroll
        for (int kt = 0; kt < 4; ++kt)
            A2[mt][kt] = *(const short8*)(Hb + ((lm * 256 + kt * 64 + lq * 16) ^ sw));
    }
    f32x4 acc2[2][8];
#pragma unroll
    for (int tt = 0; tt < 8; ++tt) {
        const float b2 = n_b2[tt * 16 + lr];
        acc2[0][tt] = (f32x4){b2, b2, b2, b2};
        acc2[1][tt] = acc2[0][tt];
    }
#pragma unroll
    for (int kt = 0; kt < 4; ++kt) {
#pragma unroll
        for (int tt = 0; tt < 8; ++tt) {
            const short8 b = *(const short8*)&Bn2[((kt * 8 + tt) * 64 + l) * 8];
            acc2[0][tt] = MFMA(A2[0][kt], b, acc2[0][tt]);
            acc2[1][tt] = MFMA(A2[1][kt], b, acc2[1][tt]);
        }
    }
#pragma unroll
    for (int mt = 0; mt < 2; ++mt)
#pragma unroll
        for (int tt = 0; tt < 8; ++tt) {
            const int n = tt * 16 + lr;
#pragma unroll
            for (int r = 0; r < 4; ++r) {
                const int lm = mt * 16 + lq * 4 + r;
                const int nd = n0 + lm;
                const unsigned ndc = (nd < NN) ? nd : (NN - 1);
                const float hv = h[ndc * HID + n];
                const float ho = hv + silu_(acc2[mt][tt][r]);
                if (nd < NN) out_h[(unsigned)nd * HID + n] = ho;
                const int off = (lm * 256 + n * 2) ^ ((lm & 7) << 4);
                *(short*)(Hb + off) = f2bf(ho);
            }
        }
    asm volatile("s_waitcnt lgkmcnt(0)" ::: "memory");

    // --- AP layer ---
    short8 A3[2][4];
#pragma unroll
    for (int mt = 0; mt < 2; ++mt) {
        const int lm = mt * 16 + lr;
        const int sw = (lm & 7) << 4;
#pragma unroll
        for (int kt = 0; kt < 4; ++kt)
            A3[mt][kt] = *(const short8*)(Hb + ((lm * 256 + kt * 64 + lq * 16) ^ sw));
    }
    f32x4 acc3[2][8];
#pragma unroll
    for (int tt = 0; tt < 8; ++tt) {
        const float pa = pre[3 * HID + tt * 16 + lr];
        acc3[0][tt] = (f32x4){pa, pa, pa, pa};
        acc3[1][tt] = acc3[0][tt];
    }
#pragma unroll
    for (int kt = 0; kt < 4; ++kt) {
#pragma unroll
        for (int tt = 0; tt < 8; ++tt) {
            const short8 b = *(const short8*)&Bap[((kt * 8 + tt) * 64 + l) * 8];
            acc3[0][tt] = MFMA(A3[0][kt], b, acc3[0][tt]);
            acc3[1][tt] = MFMA(A3[1][kt], b, acc3[1][tt]);
        }
    }
    float w2v[8];
#pragma unroll
    for (int tt = 0; tt < 8; ++tt) w2v[tt] = ap_w2[tt * 16 + lr];

#pragma unroll
    for (int mt = 0; mt < 2; ++mt) {
        float p0 = 0.f, p1 = 0.f, p2 = 0.f, p3 = 0.f;
#pragma unroll
        for (int tt = 0; tt < 8; ++tt) {
            p0 += silu_(acc3[mt][tt][0]) * w2v[tt];
            p1 += silu_(acc3[mt][tt][1]) * w2v[tt];
            p2 += silu_(acc3[mt][tt][2]) * w2v[tt];
            p3 += silu_(acc3[mt][tt][3]) * w2v[tt];
        }
#pragma unroll
        for (int r = 0; r < 4; ++r) {
            float s = (r == 0) ? p0 : (r == 1) ? p1 : (r == 2) ? p2 : p3;
            s += __shfl_xor(s, 1, 16);
            s += __shfl_xor(s, 2, 16);
            s += __shfl_xor(s, 4, 16);
            s += __shfl_xor(s, 8, 16);
            const int lm = mt * 16 + lq * 4 + r;
            const int nd = n0 + lm;
            if (lr < 3 && nd < NN) {
                out_acc[(unsigned)nd * 3 + lr] = agg_c[(unsigned)nd * 3 + lr] * s;
                out_coord[(unsigned)nd * 3 + lr] = coord[(unsigned)nd * 3 + lr];
            }
        }
    }
}

// ---------------------------------------------------------------------------
extern "C" void kernel_launch(void* const* d_in, const int* in_sizes, int n_in,
                              void* d_out, int out_size, void* d_ws, size_t ws_size,
                              hipStream_t stream)
{
    const float* h      = (const float*)d_in[0];
    const int*   ei     = (const int*)d_in[1];
    const float* coord  = (const float*)d_in[2];
    const float* eattr  = (const float*)d_in[3];
    const float* prompt = (const float*)d_in[4];
    const float* e_w1 = (const float*)d_in[5];
    const float* e_b1 = (const float*)d_in[6];
    const float* e_w2 = (const float*)d_in[7];
    const float* e_b2 = (const float*)d_in[8];
    const float* n_w1 = (const float*)d_in[9];
    const float* n_b1 = (const float*)d_in[10];
    const float* n_w2 = (const float*)d_in[11];
    const float* n_b2 = (const float*)d_in[12];
    const float* ae_w1 = (const float*)d_in[13];
    const float* ae_b1 = (const float*)d_in[14];
    const float* ae_w2 = (const float*)d_in[15];
    const float* ap_w1 = (const float*)d_in[16];
    const float* ap_b1 = (const float*)d_in[17];
    const float* ap_w2 = (const float*)d_in[18];

    float* out       = (float*)d_out;
    float* out_h     = out;                          // [NN,128]
    float* out_coord = out + (size_t)NN * HID;       // [NN,3]
    float* out_acc   = out_coord + (size_t)NN * 3;   // [NN,3]

    float* agg_c = (float*)d_ws;                     // [NN,3] f32
    float* pre   = agg_c + (size_t)NN * 3;           // [512]
    short* wsw   = (short*)(pre + 512);              // 264 frags x 512 shorts
    short* aggb  = wsw + 264 * 512;                  // [NN,128] bf16 agg
    short* hb    = aggb + (size_t)NN * HID;          // [NN,128] bf16 h
    short* P1    = hb + (size_t)NN * HID;            // [NN,128] bf16
    short* P2    = P1 + (size_t)NN * HID;            // [NN,128] bf16

    // eattr bf16 [NE,16] = 25.6MB: overlaid on out_h region (only needed
    // during edge pass; out_h is written exclusively by node_kernel later)
    short* eb = (short*)out_h;

    const short* Bw1 = wsw;            // e_w1: 72 frags
    const short* Bw2 = wsw + 36864;    // e_w2: 32
    const short* Bae = wsw + 53248;    // ae_w1: 32
    const short* Bn1 = wsw + 69632;    // n_w1: 64
    const short* Bn2 = wsw + 102400;   // n_w2: 32
    const short* Bap = wsw + 118784;   // ap_w1: 32

    hipMemsetAsync(aggb, 0, (size_t)NN * HID * sizeof(short), stream);
    hipMemsetAsync(agg_c, 0, (size_t)NN * 3 * sizeof(float), stream);

    pre_kernel<<<1, 128, 0, stream>>>(prompt, e_w1, e_b1, n_w1, n_b1,
                                      ae_w1, ae_b1, ap_w1, ap_b1, pre);
    prep_weights<<<264, 64, 0, stream>>>(e_w1, e_w2, ae_w1, n_w1, n_w2, ap_w1, wsw);
    conv_bf16<<<(NN * HID / 8 + 255) / 256, 256, 0, stream>>>(h, hb, NN * HID / 8);
    conv_bf16<<<(NE * 16 / 8 + 255) / 256, 256, 0, stream>>>(eattr, eb, NE * 16 / 8);
    prep_P<<<(NN + 63) / 64, 128, 0, stream>>>(hb, Bw1, P1, P2);

    edge_kernel<<<NE / 32, 128, 0, stream>>>(P1, P2, ei, coord, eb,
                                             Bw1, Bw2, Bae, e_b2, ae_w2,
                                             pre, aggb, agg_c);
    node_kernel<<<(NN + 63) / 64, 128, 0, stream>>>(h, hb, coord, Bn1, Bn2, Bap,
                                                    n_b2, ap_w2, pre,
                                                    aggb, agg_c,
                                                    out_h, out_coord, out_acc);
}